// Round 8
// baseline (152.129 us; speedup 1.0000x reference)
//
#include <hip/hip_runtime.h>
#include <cstdint>
#include <cstddef>

#define H_CH 1024
#define OUTF 512
#define LSEQ 4096

typedef __bf16 bf16x8 __attribute__((ext_vector_type(8)));
typedef float floatx4 __attribute__((ext_vector_type(4)));

__device__ __forceinline__ unsigned short f2bf(float f) {
    __bf16 b = (__bf16)f;
    return __builtin_bit_cast(unsigned short, b);
}
__device__ __forceinline__ unsigned int pack2(float a, float b) {
    return (unsigned int)f2bf(a) | ((unsigned int)f2bf(b) << 16);
}
__device__ __forceinline__ float bf2f(unsigned short u) {
    unsigned int x = ((unsigned int)u) << 16;
    return __builtin_bit_cast(float, x);
}
struct c32 { float x, y; };
__device__ __forceinline__ c32 cmul(c32 a, c32 b) {
    return { fmaf(a.x, b.x, -a.y * b.y), fmaf(a.x, b.y, a.y * b.x) };
}
__device__ __forceinline__ c32 cpow16(c32 a, int w) {   // a^(16*w), w in 0..3
    c32 p = {1.f, 0.f};
    if (w) {
        c32 a2 = cmul(a, a), a4 = cmul(a2, a2), a8 = cmul(a4, a4), a16 = cmul(a8, a8);
        p = a16;
        for (int k = 1; k < w; ++k) p = cmul(p, a16);
    }
    return p;
}
// gelu(y) = y * sigmoid(1.59576912*(y + 0.044715 y^3))  (== tanh-GELU exactly)
__device__ __forceinline__ float gelu_fast(float y) {
    float u = y + 0.044715f * y * y * y;
    float e = __expf(-1.5957691216057308f * u);
    return y * __builtin_amdgcn_rcpf(1.f + e);
}

// ---------------------------------------------------------------------------
// prep: blocks 0..255 -> coef per (c,n); blocks 256..383 -> W transpose.
// coef = fp64-exact {lam, inv=lam^-1, lamQ=lam^64, 2*conj-folded Ct}.
// ---------------------------------------------------------------------------
__global__ __launch_bounds__(256) void prep_kernel(
    const float* __restrict__ log_dt, const float* __restrict__ A_re,
    const float* __restrict__ A_im, const float* __restrict__ C_re,
    const float* __restrict__ C_im, const float* __restrict__ W,
    float* __restrict__ coef, unsigned short* __restrict__ Wt)
{
    __shared__ float tileF[64 * 65];
    const int t = threadIdx.x;
    if (blockIdx.x < 256) {
        const int i = blockIdx.x * 256 + t;             // c*64+n
        const int c = i >> 6;
        double are = A_re[i], aim = A_im[i], cre = C_re[i], cim = C_im[i];
        double dt  = exp((double)log_dt[c]);
        double dar = dt * are, dai = dt * aim;
        double er = exp(dar), cd = cos(dai), sd = sin(dai);
        double lre = er * cd, limm = er * sd;
        double ei = exp(-dar);
        double eQ = exp(64.0 * dar), cQ = cos(64.0 * dai), sQ = sin(64.0 * dai);
        double nre = lre - 1.0, nim = limm;
        double d2  = are * are + aim * aim;
        double qre = (nre * are + nim * aim) / d2;
        double qim = (nim * are - nre * aim) / d2;
        double ctre = cre * qre - cim * qim, ctim = cre * qim + cim * qre;
        float4 w0 = make_float4((float)lre, (float)limm, (float)(ei * cd), (float)(-ei * sd));
        float4 w1 = make_float4((float)(eQ * cQ), (float)(eQ * sQ),
                                (float)(2.0 * ctre), (float)(-2.0 * ctim));
        *(float4*)&coef[(size_t)i * 8]     = w0;
        *(float4*)&coef[(size_t)i * 8 + 4] = w1;
    } else {
        const int bid = blockIdx.x - 256;               // 0..127
        const int o0 = (bid & 7) * 64, k0 = (bid >> 3) * 64;
        {
            const int ty = t >> 6, tx = t & 63;
            #pragma unroll
            for (int r = 0; r < 16; ++r) {
                const int ki = r * 4 + ty;
                tileF[ki * 65 + tx] = W[(size_t)(k0 + ki) * OUTF + o0 + tx];
            }
        }
        __syncthreads();
        {
            const int ty = t >> 5, tx = t & 31;
            #pragma unroll
            for (int r = 0; r < 8; ++r) {
                const int oi = r * 8 + ty;
                unsigned int u0 = f2bf(tileF[(2 * tx) * 65 + oi]);
                unsigned int u1 = f2bf(tileF[(2 * tx + 1) * 65 + oi]);
                *(unsigned int*)&Wt[(size_t)(o0 + oi) * H_CH + k0 + 2 * tx] = u0 | (u1 << 16);
            }
        }
    }
}

// ---------------------------------------------------------------------------
// s4_fused: one block per channel c, loops over both batches.  (R6-exact:
// F regenerated in-loop; the R7 fz register hoist regressed 20 us.)
// Output g' in l-tile-blocked layout: g'[b][l>>7][c][l&127] (bf16).
// ---------------------------------------------------------------------------
__global__ __launch_bounds__(256) void s4_fused_kernel(
    const float* __restrict__ x, const float* __restrict__ coef,
    const float* __restrict__ Dp, unsigned short* __restrict__ gprime)
{
    __shared__ __align__(16) unsigned short Vs[64 * 72];      // [chunk][t]
    __shared__ __align__(16) unsigned short Ps[65 * 136];     // P rows (bf16 pairs)
    __shared__ __align__(16) unsigned char  RY[128 * 72 * 2]; // F / R / ybuf overlay
    __shared__ __align__(16) unsigned short Ss[64 * 136];     // Delta -> Shat
    __shared__ __align__(16) unsigned short Ts[64 * 72];      // T = tril(P@R) bf16
    __shared__ float2 Es[4][64];
    __shared__ float  pe16[16];
    unsigned short* Fs   = (unsigned short*)RY;               // 128*72
    unsigned short* Rs   = (unsigned short*)RY;               // 64*136
    unsigned int*   ybuf = (unsigned int*)RY;                 // 64*34 u32

    const int c = blockIdx.x;                                 // 0..1023
    const int t = threadIdx.x, lane = t & 63, w = t >> 6, n = lane;
    const int lm = lane & 15, lq = lane >> 4;

    const int axis = (c >= 684) ? 2 : ((c >= 342) ? 1 : 0);
    const int j = c - 342 * axis;
    const int is_cos = j & 1;
    if (t < 16) {
        const float freq = (float)exp(-log(10000.0) * (double)(2 * (j >> 1)) / 342.0);
        float a = (float)t * freq;
        pe16[t] = is_cos ? cosf(a) : sinf(a);
    }
    const float* cf = coef + ((size_t)c * 64 + n) * 8;
    c32 lam = {cf[0], cf[1]}, inv = {cf[2], cf[3]}, lamQ = {cf[4], cf[5]};
    const float c2r = cf[6], c2mi = cf[7];
    const float Dc = Dp[c];
    __syncthreads();                                          // pe16 visible

    // --- per-batch: stage V, gen F, Delta, segmented scan -> Shat in Ss ---
    auto deltascan = [&](int bb) {
        const float* xp = x + ((size_t)bb * H_CH + c) * (size_t)LSEQ;
        #pragma unroll
        for (int r = 0; r < 2; ++r) {
            const int i = r * 256 + t, l0 = i * 8;
            float4 f0 = *(const float4*)(xp + l0);
            float4 f1 = *(const float4*)(xp + l0 + 4);
            float e[8] = {f0.x, f0.y, f0.z, f0.w, f1.x, f1.y, f1.z, f1.w};
            unsigned int o[4];
            #pragma unroll
            for (int k = 0; k < 4; ++k) {
                const int la = l0 + 2 * k, lb = la + 1;
                const int pa = axis == 0 ? (la >> 8) : axis == 1 ? ((la >> 4) & 15) : (la & 15);
                const int pb = axis == 0 ? (lb >> 8) : axis == 1 ? ((lb >> 4) & 15) : (lb & 15);
                o[k] = pack2(e[2 * k] + pe16[pa], e[2 * k + 1] + pe16[pb]);
            }
            *(uint4*)&Vs[(i >> 3) * 72 + (i & 7) * 8] = make_uint4(o[0], o[1], o[2], o[3]);
        }
        {   // F rows 2n,2n+1: (Re,Im) lam^(63-u), u in [16w,16w+16)
            c32 l2 = cmul(lam, lam), l4 = cmul(l2, l2), l8 = cmul(l4, l4);
            c32 l16 = cmul(l8, l8), l32 = cmul(l16, l16);
            c32 z = cmul(cmul(cmul(cmul(cmul(l32, l16), l8), l4), l2), lam); // lam^63
            z = cmul(z, cpow16(inv, w));
            #pragma unroll
            for (int s = 0; s < 16; ++s) {
                const int u = 16 * w + s;
                Fs[(2 * n) * 72 + u]     = f2bf(z.x);
                Fs[(2 * n + 1) * 72 + u] = f2bf(z.y);
                z = cmul(z, inv);
            }
        }
        __syncthreads();
        {   // Delta = F(128x64) @ V(64x64) -> scatter into Ss [chunk][comp]
            floatx4 acc[2][4];
            #pragma unroll
            for (int a = 0; a < 2; ++a)
                #pragma unroll
                for (int b = 0; b < 4; ++b) acc[a][b] = (floatx4){0.f, 0.f, 0.f, 0.f};
            #pragma unroll
            for (int kt = 0; kt < 2; ++kt) {
                bf16x8 a0 = *(const bf16x8*)&Fs[(32 * w + lm) * 72 + kt * 32 + lq * 8];
                bf16x8 a1 = *(const bf16x8*)&Fs[(32 * w + 16 + lm) * 72 + kt * 32 + lq * 8];
                #pragma unroll
                for (int nt = 0; nt < 4; ++nt) {
                    bf16x8 b = *(const bf16x8*)&Vs[(nt * 16 + lm) * 72 + kt * 32 + lq * 8];
                    acc[0][nt] = __builtin_amdgcn_mfma_f32_16x16x32_bf16(a0, b, acc[0][nt], 0, 0, 0);
                    acc[1][nt] = __builtin_amdgcn_mfma_f32_16x16x32_bf16(a1, b, acc[1][nt], 0, 0, 0);
                }
            }
            #pragma unroll
            for (int sm = 0; sm < 2; ++sm)
                #pragma unroll
                for (int nt = 0; nt < 4; ++nt) {
                    const int row = 32 * w + sm * 16 + lq * 4, col = nt * 16 + lm;
                    *(uint2*)&Ss[col * 136 + row] =
                        make_uint2(pack2(acc[sm][nt][0], acc[sm][nt][1]),
                                   pack2(acc[sm][nt][2], acc[sm][nt][3]));
                }
        }
        __syncthreads();
        {   // scan A: local (zero-init) scan of 16-chunk segment
            float sr = 0.f, si = 0.f;
            #pragma unroll
            for (int jc = 0; jc < 16; ++jc) {
                unsigned int d = *(unsigned int*)&Ss[(16 * w + jc) * 136 + 2 * n];
                float dr = bf2f((unsigned short)(d & 0xffff));
                float di = bf2f((unsigned short)(d >> 16));
                float nr = fmaf(lamQ.x, sr, fmaf(-lamQ.y, si, dr));
                float ni = fmaf(lamQ.x, si, fmaf(lamQ.y, sr, di));
                sr = nr; si = ni;
            }
            Es[w][n] = make_float2(sr, si);
        }
        __syncthreads();
        {   // carry + scan B -> exclusive Shat written back to Ss
            c32 Q2 = cmul(lamQ, lamQ), Q4 = cmul(Q2, Q2), Q8 = cmul(Q4, Q4);
            c32 Q16 = cmul(Q8, Q8);                       // lam^1024
            float cr = 0.f, ci = 0.f;
            for (int w2 = 0; w2 < w; ++w2) {
                float2 e = Es[w2][n];
                float nr = fmaf(Q16.x, cr, fmaf(-Q16.y, ci, e.x));
                float ni = fmaf(Q16.x, ci, fmaf(Q16.y, cr, e.y));
                cr = nr; ci = ni;
            }
            float sr = cr, si = ci;
            #pragma unroll
            for (int jc = 0; jc < 16; ++jc) {
                unsigned int* p = (unsigned int*)&Ss[(16 * w + jc) * 136 + 2 * n];
                unsigned int d = *p;
                *p = pack2(sr, si);
                float dr = bf2f((unsigned short)(d & 0xffff));
                float di = bf2f((unsigned short)(d >> 16));
                float nr = fmaf(lamQ.x, sr, fmaf(-lamQ.y, si, dr));
                float ni = fmaf(lamQ.x, si, fmaf(lamQ.y, sr, di));
                sr = nr; si = ni;
            }
        }
        __syncthreads();
    };

    // --- per-batch: Y = T@V + E@Shat ; gelu ; store g' (blocked layout) ---
    auto gemm2_epi = [&](int bb) {
        floatx4 a2[4];
        #pragma unroll
        for (int nt = 0; nt < 4; ++nt) a2[nt] = (floatx4){0.f, 0.f, 0.f, 0.f};
        #pragma unroll
        for (int kt = 0; kt < 2; ++kt) {
            bf16x8 a = *(const bf16x8*)&Ts[(16 * w + lm) * 72 + kt * 32 + lq * 8];
            #pragma unroll
            for (int nt = 0; nt < 4; ++nt) {
                bf16x8 b = *(const bf16x8*)&Vs[(nt * 16 + lm) * 72 + kt * 32 + lq * 8];
                a2[nt] = __builtin_amdgcn_mfma_f32_16x16x32_bf16(a, b, a2[nt], 0, 0, 0);
            }
        }
        #pragma unroll
        for (int kt = 0; kt < 4; ++kt) {
            bf16x8 a = *(const bf16x8*)&Ps[(16 * w + lm + 1) * 136 + kt * 32 + lq * 8];
            #pragma unroll
            for (int nt = 0; nt < 4; ++nt) {
                bf16x8 b = *(const bf16x8*)&Ss[(nt * 16 + lm) * 136 + kt * 32 + lq * 8];
                a2[nt] = __builtin_amdgcn_mfma_f32_16x16x32_bf16(a, b, a2[nt], 0, 0, 0);
            }
        }
        __syncthreads();   // RY readers done; safe to write ybuf
        #pragma unroll
        for (int nt = 0; nt < 4; ++nt) {
            const int chunk = nt * 16 + lm;
            float gg[4];
            #pragma unroll
            for (int r = 0; r < 4; ++r) {
                const int tt = 16 * w + lq * 4 + r;
                const float vv = bf2f(Vs[chunk * 72 + tt]);
                gg[r] = gelu_fast(fmaf(Dc, vv, a2[nt][r]));
            }
            const int p0 = 8 * w + 2 * lq;
            ybuf[chunk * 34 + p0]     = pack2(gg[0], gg[1]);
            ybuf[chunk * 34 + p0 + 1] = pack2(gg[2], gg[3]);
        }
        __syncthreads();
        unsigned int* gp = (unsigned int*)gprime
                         + (size_t)bb * 32 * 1024 * 64 + (size_t)c * 64;
        #pragma unroll
        for (int q = 0; q < 8; ++q) {
            const int idx = q * 256 + t;               // 0..2047, l = 2*idx
            const int lt = idx >> 6, w32 = idx & 63;
            gp[(size_t)lt * (1024 * 64) + w32] = ybuf[(idx >> 5) * 34 + (idx & 31)];
        }
        __syncthreads();
    };

    // ---- pipeline ----
    deltascan(0);

    {   // P rows tt: (Re,-Im) of 2*Ct*lam^tt ; wave w covers [16w,16w+16) (+row 64 on w=3)
        c32 z = cmul((c32){c2r, -c2mi}, cpow16(lam, w));
        const int steps = (w == 3) ? 17 : 16;
        for (int s = 0; s < steps; ++s) {
            const int tt = 16 * w + s;
            *(unsigned int*)&Ps[tt * 136 + 2 * n] = pack2(z.x, -z.y);
            z = cmul(z, lam);
        }
    }
    {   // R rows u: (Re,Im) lam^-u  (overwrites F, dead post-Delta0)
        c32 z = cpow16(inv, w);
        #pragma unroll
        for (int s = 0; s < 16; ++s) {
            const int u = 16 * w + s;
            *(unsigned int*)&Rs[u * 136 + 2 * n] = pack2(z.x, z.y);
            z = cmul(z, inv);
        }
    }
    __syncthreads();
    {   // GEMM1: T = tril(P@R), M=N=64, K=128  (once per channel)
        floatx4 a1[4];
        #pragma unroll
        for (int nt = 0; nt < 4; ++nt) a1[nt] = (floatx4){0.f, 0.f, 0.f, 0.f};
        #pragma unroll
        for (int kt = 0; kt < 4; ++kt) {
            bf16x8 a = *(const bf16x8*)&Ps[(16 * w + lm) * 136 + kt * 32 + lq * 8];
            #pragma unroll
            for (int nt = 0; nt < 4; ++nt) {
                bf16x8 b = *(const bf16x8*)&Rs[(nt * 16 + lm) * 136 + kt * 32 + lq * 8];
                a1[nt] = __builtin_amdgcn_mfma_f32_16x16x32_bf16(a, b, a1[nt], 0, 0, 0);
            }
        }
        #pragma unroll
        for (int nt = 0; nt < 4; ++nt)
            #pragma unroll
            for (int r = 0; r < 4; ++r) {
                const int row = 16 * w + lq * 4 + r, col = nt * 16 + lm;
                Ts[row * 72 + col] = f2bf(row >= col ? a1[nt][r] : 0.f);
            }
    }
    __syncthreads();

    gemm2_epi(0);
    deltascan(1);
    gemm2_epi(1);
}

// ---------------------------------------------------------------------------
// GEMM: out[b,o,l] = sum_k Wt[o,k]*g'[b,lt,k,l'] + b_out[o].
// 64(o) x 128(l) tiles, BK=64, register prefetch, conflict-light B transpose.
// Grid (o-tile, l-tile, b) so consecutive blocks share a B-panel in L2.
// ---------------------------------------------------------------------------
__global__ __launch_bounds__(256) void gemm_kernel(
    const unsigned short* __restrict__ gp, const unsigned short* __restrict__ Wt,
    const float* __restrict__ b_out, float* __restrict__ out)
{
    __shared__ unsigned short As[64 * 72];      // [o][k] rows, stride 144 B
    __shared__ unsigned short Bs[128 * 72];     // [l][k]
    const int t = threadIdx.x, lane = t & 63, w = t >> 6;
    const int lm = lane & 15, lq = lane >> 4;
    const int o0 = blockIdx.x * 64;
    const int by = blockIdx.y;                  // l-tile 0..31
    const int bb = blockIdx.z;
    const int l0 = by * 128;
    const unsigned short* bsrc = gp + (size_t)(bb * 32 + by) * (1024 * 128);

    const int kp = t & 31, bg = t >> 5;         // B: k-pair 0..31, l-octet 0..7

    uint4 aR[2], bR[4];
    auto loadA = [&](int k0) {
        #pragma unroll
        for (int h = 0; h < 2; ++h) {
            const int idx = t + h * 256, row = idx >> 3, q = idx & 7;
            aR[h] = *(const uint4*)(Wt + (size_t)(o0 + row) * H_CH + k0 + q * 8);
        }
    };
    auto loadB = [&](int k0) {
        const unsigned short* s0 = bsrc + (size_t)(k0 + 2 * kp) * 128 + bg * 16;
        bR[0] = *(const uint4*)(s0);
        bR[1] = *(const uint4*)(s0 + 8);
        bR[2] = *(const uint4*)(s0 + 128);
        bR[3] = *(const uint4*)(s0 + 136);
    };

    floatx4 acc[4][2];
    #pragma unroll
    for (int i = 0; i < 4; ++i)
        #pragma unroll
        for (int jj = 0; jj < 2; ++jj) acc[i][jj] = (floatx4){0.f, 0.f, 0.f, 0.f};

    loadA(0); loadB(0);
    for (int kt = 0; kt < 16; ++kt) {
        if (kt) __syncthreads();
        {   // store A
            #pragma unroll
            for (int h = 0; h < 2; ++h) {
                const int idx = t + h * 256, row = idx >> 3, q = idx & 7;
                *(uint4*)&As[row * 72 + q * 8] = aR[h];
            }
        }
        {   // transpose-scatter B: Bs[l][k] u32 (k-pair kp)
            unsigned int* bu = (unsigned int*)Bs;
            const unsigned int* a0 = (const unsigned int*)&bR[0];
            const unsigned int* a1 = (const unsigned int*)&bR[1];
            const unsigned int* b0 = (const unsigned int*)&bR[2];
            const unsigned int* b1 = (const unsigned int*)&bR[3];
            #pragma unroll
            for (int i = 0; i < 4; ++i) {
                unsigned int lo0 = (a0[i] & 0xffffu) | (b0[i] << 16);
                unsigned int hi0 = (a0[i] >> 16) | (b0[i] & 0xffff0000u);
                unsigned int lo1 = (a1[i] & 0xffffu) | (b1[i] << 16);
                unsigned int hi1 = (a1[i] >> 16) | (b1[i] & 0xffff0000u);
                bu[(bg * 16 + 2 * i) * 36 + kp]     = lo0;
                bu[(bg * 16 + 2 * i + 1) * 36 + kp] = hi0;
                bu[(bg * 16 + 8 + 2 * i) * 36 + kp]     = lo1;
                bu[(bg * 16 + 8 + 2 * i + 1) * 36 + kp] = hi1;
            }
        }
        __syncthreads();
        if (kt < 15) { loadA((kt + 1) * 64); loadB((kt + 1) * 64); }

        #pragma unroll
        for (int q2 = 0; q2 < 2; ++q2) {
            bf16x8 af[4], bfr[2];
            #pragma unroll
            for (int sm = 0; sm < 4; ++sm)
                af[sm] = *(const bf16x8*)&As[(sm * 16 + lm) * 72 + q2 * 32 + lq * 8];
            #pragma unroll
            for (int sn = 0; sn < 2; ++sn)
                bfr[sn] = *(const bf16x8*)&Bs[(w * 32 + sn * 16 + lm) * 72 + q2 * 32 + lq * 8];
            #pragma unroll
            for (int sm = 0; sm < 4; ++sm)
                #pragma unroll
                for (int sn = 0; sn < 2; ++sn)
                    acc[sm][sn] = __builtin_amdgcn_mfma_f32_16x16x32_bf16(
                        af[sm], bfr[sn], acc[sm][sn], 0, 0, 0);
        }
    }

    #pragma unroll
    for (int sm = 0; sm < 4; ++sm)
        #pragma unroll
        for (int sn = 0; sn < 2; ++sn)
            #pragma unroll
            for (int r = 0; r < 4; ++r) {
                const int o = o0 + sm * 16 + lq * 4 + r;
                const int l = l0 + w * 32 + sn * 16 + lm;
                out[((size_t)bb * OUTF + o) * LSEQ + l] = acc[sm][sn][r] + b_out[o];
            }
}

// ---------------------------------------------------------------------------
extern "C" void kernel_launch(void* const* d_in, const int* in_sizes, int n_in,
                              void* d_out, int out_size, void* d_ws, size_t ws_size,
                              hipStream_t stream) {
    const float* x      = (const float*)d_in[0];
    const float* log_dt = (const float*)d_in[1];
    const float* A_re   = (const float*)d_in[2];
    const float* A_im   = (const float*)d_in[3];
    const float* C_re   = (const float*)d_in[4];
    const float* C_im   = (const float*)d_in[5];
    const float* Dp     = (const float*)d_in[6];
    const float* W_out  = (const float*)d_in[7];
    const float* b_out  = (const float*)d_in[8];
    float* out = (float*)d_out;

    // Workspace: g' [0,16M), Wt [17M,18M), coef [19M,21M)
    char* ws = (char*)d_ws;
    unsigned short* gprime = (unsigned short*)ws;
    unsigned short* Wt     = (unsigned short*)(ws + (size_t)17 * 1024 * 1024);
    float*          coef   = (float*)(ws + (size_t)19 * 1024 * 1024);

    prep_kernel<<<384, 256, 0, stream>>>(log_dt, A_re, A_im, C_re, C_im, W_out,
                                         coef, Wt);
    s4_fused_kernel<<<1024, 256, 0, stream>>>(x, coef, Dp, gprime);
    gemm_kernel<<<dim3(8, 32, 2), 256, 0, stream>>>(gprime, Wt, b_out, out);
}

// Round 9
// 151.298 us; speedup vs baseline: 1.0055x; 1.0055x over previous
//
#include <hip/hip_runtime.h>
#include <cstdint>
#include <cstddef>

#define H_CH 1024
#define OUTF 512
#define LSEQ 4096

typedef __bf16 bf16x8 __attribute__((ext_vector_type(8)));
typedef float floatx4 __attribute__((ext_vector_type(4)));

__device__ __forceinline__ unsigned short f2bf(float f) {
    __bf16 b = (__bf16)f;
    return __builtin_bit_cast(unsigned short, b);
}
__device__ __forceinline__ unsigned int pack2(float a, float b) {
    return (unsigned int)f2bf(a) | ((unsigned int)f2bf(b) << 16);
}
__device__ __forceinline__ float bf2f(unsigned short u) {
    unsigned int x = ((unsigned int)u) << 16;
    return __builtin_bit_cast(float, x);
}
struct c32 { float x, y; };
__device__ __forceinline__ c32 cmul(c32 a, c32 b) {
    return { fmaf(a.x, b.x, -a.y * b.y), fmaf(a.x, b.y, a.y * b.x) };
}
__device__ __forceinline__ c32 cpow16(c32 a, int w) {   // a^(16*w), w in 0..3
    c32 p = {1.f, 0.f};
    if (w) {
        c32 a2 = cmul(a, a), a4 = cmul(a2, a2), a8 = cmul(a4, a4), a16 = cmul(a8, a8);
        p = a16;
        for (int k = 1; k < w; ++k) p = cmul(p, a16);
    }
    return p;
}
// gelu(y) = y * sigmoid(1.59576912*(y + 0.044715 y^3))  (== tanh-GELU exactly)
__device__ __forceinline__ float gelu_fast(float y) {
    float u = y + 0.044715f * y * y * y;
    float e = __expf(-1.5957691216057308f * u);
    return y * __builtin_amdgcn_rcpf(1.f + e);
}

// ---------------------------------------------------------------------------
// prep: blocks 0..255 -> coef per (c,n); blocks 256..383 -> W transpose.
// coef = fp64-exact {lam, inv=lam^-1, lamQ=lam^64, 2*conj-folded Ct}.
// ---------------------------------------------------------------------------
__global__ __launch_bounds__(256) void prep_kernel(
    const float* __restrict__ log_dt, const float* __restrict__ A_re,
    const float* __restrict__ A_im, const float* __restrict__ C_re,
    const float* __restrict__ C_im, const float* __restrict__ W,
    float* __restrict__ coef, unsigned short* __restrict__ Wt)
{
    __shared__ float tileF[64 * 65];
    const int t = threadIdx.x;
    if (blockIdx.x < 256) {
        const int i = blockIdx.x * 256 + t;             // c*64+n
        const int c = i >> 6;
        double are = A_re[i], aim = A_im[i], cre = C_re[i], cim = C_im[i];
        double dt  = exp((double)log_dt[c]);
        double dar = dt * are, dai = dt * aim;
        double er = exp(dar), cd = cos(dai), sd = sin(dai);
        double lre = er * cd, limm = er * sd;
        double ei = exp(-dar);
        double eQ = exp(64.0 * dar), cQ = cos(64.0 * dai), sQ = sin(64.0 * dai);
        double nre = lre - 1.0, nim = limm;
        double d2  = are * are + aim * aim;
        double qre = (nre * are + nim * aim) / d2;
        double qim = (nim * are - nre * aim) / d2;
        double ctre = cre * qre - cim * qim, ctim = cre * qim + cim * qre;
        float4 w0 = make_float4((float)lre, (float)limm, (float)(ei * cd), (float)(-ei * sd));
        float4 w1 = make_float4((float)(eQ * cQ), (float)(eQ * sQ),
                                (float)(2.0 * ctre), (float)(-2.0 * ctim));
        *(float4*)&coef[(size_t)i * 8]     = w0;
        *(float4*)&coef[(size_t)i * 8 + 4] = w1;
    } else {
        const int bid = blockIdx.x - 256;               // 0..127
        const int o0 = (bid & 7) * 64, k0 = (bid >> 3) * 64;
        {
            const int ty = t >> 6, tx = t & 63;
            #pragma unroll
            for (int r = 0; r < 16; ++r) {
                const int ki = r * 4 + ty;
                tileF[ki * 65 + tx] = W[(size_t)(k0 + ki) * OUTF + o0 + tx];
            }
        }
        __syncthreads();
        {
            const int ty = t >> 5, tx = t & 31;
            #pragma unroll
            for (int r = 0; r < 8; ++r) {
                const int oi = r * 8 + ty;
                unsigned int u0 = f2bf(tileF[(2 * tx) * 65 + oi]);
                unsigned int u1 = f2bf(tileF[(2 * tx + 1) * 65 + oi]);
                *(unsigned int*)&Wt[(size_t)(o0 + oi) * H_CH + k0 + 2 * tx] = u0 | (u1 << 16);
            }
        }
    }
}

// ---------------------------------------------------------------------------
// s4_fused: one block per channel c, loops over both batches.  (R6-exact)
// Output g' in l-tile-blocked layout: g'[b][l>>7][c][l&127] (bf16).
// ---------------------------------------------------------------------------
__global__ __launch_bounds__(256) void s4_fused_kernel(
    const float* __restrict__ x, const float* __restrict__ coef,
    const float* __restrict__ Dp, unsigned short* __restrict__ gprime)
{
    __shared__ __align__(16) unsigned short Vs[64 * 72];      // [chunk][t]
    __shared__ __align__(16) unsigned short Ps[65 * 136];     // P rows (bf16 pairs)
    __shared__ __align__(16) unsigned char  RY[128 * 72 * 2]; // F / R / ybuf overlay
    __shared__ __align__(16) unsigned short Ss[64 * 136];     // Delta -> Shat
    __shared__ __align__(16) unsigned short Ts[64 * 72];      // T = tril(P@R) bf16
    __shared__ float2 Es[4][64];
    __shared__ float  pe16[16];
    unsigned short* Fs   = (unsigned short*)RY;               // 128*72
    unsigned short* Rs   = (unsigned short*)RY;               // 64*136
    unsigned int*   ybuf = (unsigned int*)RY;                 // 64*34 u32

    const int c = blockIdx.x;                                 // 0..1023
    const int t = threadIdx.x, lane = t & 63, w = t >> 6, n = lane;
    const int lm = lane & 15, lq = lane >> 4;

    const int axis = (c >= 684) ? 2 : ((c >= 342) ? 1 : 0);
    const int j = c - 342 * axis;
    const int is_cos = j & 1;
    if (t < 16) {
        const float freq = (float)exp(-log(10000.0) * (double)(2 * (j >> 1)) / 342.0);
        float a = (float)t * freq;
        pe16[t] = is_cos ? cosf(a) : sinf(a);
    }
    const float* cf = coef + ((size_t)c * 64 + n) * 8;
    c32 lam = {cf[0], cf[1]}, inv = {cf[2], cf[3]}, lamQ = {cf[4], cf[5]};
    const float c2r = cf[6], c2mi = cf[7];
    const float Dc = Dp[c];
    __syncthreads();                                          // pe16 visible

    // --- per-batch: stage V, gen F, Delta, segmented scan -> Shat in Ss ---
    auto deltascan = [&](int bb) {
        const float* xp = x + ((size_t)bb * H_CH + c) * (size_t)LSEQ;
        #pragma unroll
        for (int r = 0; r < 2; ++r) {
            const int i = r * 256 + t, l0 = i * 8;
            float4 f0 = *(const float4*)(xp + l0);
            float4 f1 = *(const float4*)(xp + l0 + 4);
            float e[8] = {f0.x, f0.y, f0.z, f0.w, f1.x, f1.y, f1.z, f1.w};
            unsigned int o[4];
            #pragma unroll
            for (int k = 0; k < 4; ++k) {
                const int la = l0 + 2 * k, lb = la + 1;
                const int pa = axis == 0 ? (la >> 8) : axis == 1 ? ((la >> 4) & 15) : (la & 15);
                const int pb = axis == 0 ? (lb >> 8) : axis == 1 ? ((lb >> 4) & 15) : (lb & 15);
                o[k] = pack2(e[2 * k] + pe16[pa], e[2 * k + 1] + pe16[pb]);
            }
            *(uint4*)&Vs[(i >> 3) * 72 + (i & 7) * 8] = make_uint4(o[0], o[1], o[2], o[3]);
        }
        {   // F rows 2n,2n+1: (Re,Im) lam^(63-u), u in [16w,16w+16)
            c32 l2 = cmul(lam, lam), l4 = cmul(l2, l2), l8 = cmul(l4, l4);
            c32 l16 = cmul(l8, l8), l32 = cmul(l16, l16);
            c32 z = cmul(cmul(cmul(cmul(cmul(l32, l16), l8), l4), l2), lam); // lam^63
            z = cmul(z, cpow16(inv, w));
            #pragma unroll
            for (int s = 0; s < 16; ++s) {
                const int u = 16 * w + s;
                Fs[(2 * n) * 72 + u]     = f2bf(z.x);
                Fs[(2 * n + 1) * 72 + u] = f2bf(z.y);
                z = cmul(z, inv);
            }
        }
        __syncthreads();
        {   // Delta = F(128x64) @ V(64x64) -> scatter into Ss [chunk][comp]
            floatx4 acc[2][4];
            #pragma unroll
            for (int a = 0; a < 2; ++a)
                #pragma unroll
                for (int b = 0; b < 4; ++b) acc[a][b] = (floatx4){0.f, 0.f, 0.f, 0.f};
            #pragma unroll
            for (int kt = 0; kt < 2; ++kt) {
                bf16x8 a0 = *(const bf16x8*)&Fs[(32 * w + lm) * 72 + kt * 32 + lq * 8];
                bf16x8 a1 = *(const bf16x8*)&Fs[(32 * w + 16 + lm) * 72 + kt * 32 + lq * 8];
                #pragma unroll
                for (int nt = 0; nt < 4; ++nt) {
                    bf16x8 b = *(const bf16x8*)&Vs[(nt * 16 + lm) * 72 + kt * 32 + lq * 8];
                    acc[0][nt] = __builtin_amdgcn_mfma_f32_16x16x32_bf16(a0, b, acc[0][nt], 0, 0, 0);
                    acc[1][nt] = __builtin_amdgcn_mfma_f32_16x16x32_bf16(a1, b, acc[1][nt], 0, 0, 0);
                }
            }
            #pragma unroll
            for (int sm = 0; sm < 2; ++sm)
                #pragma unroll
                for (int nt = 0; nt < 4; ++nt) {
                    const int row = 32 * w + sm * 16 + lq * 4, col = nt * 16 + lm;
                    *(uint2*)&Ss[col * 136 + row] =
                        make_uint2(pack2(acc[sm][nt][0], acc[sm][nt][1]),
                                   pack2(acc[sm][nt][2], acc[sm][nt][3]));
                }
        }
        __syncthreads();
        {   // scan A: local (zero-init) scan of 16-chunk segment
            float sr = 0.f, si = 0.f;
            #pragma unroll
            for (int jc = 0; jc < 16; ++jc) {
                unsigned int d = *(unsigned int*)&Ss[(16 * w + jc) * 136 + 2 * n];
                float dr = bf2f((unsigned short)(d & 0xffff));
                float di = bf2f((unsigned short)(d >> 16));
                float nr = fmaf(lamQ.x, sr, fmaf(-lamQ.y, si, dr));
                float ni = fmaf(lamQ.x, si, fmaf(lamQ.y, sr, di));
                sr = nr; si = ni;
            }
            Es[w][n] = make_float2(sr, si);
        }
        __syncthreads();
        {   // carry + scan B -> exclusive Shat written back to Ss
            c32 Q2 = cmul(lamQ, lamQ), Q4 = cmul(Q2, Q2), Q8 = cmul(Q4, Q4);
            c32 Q16 = cmul(Q8, Q8);                       // lam^1024
            float cr = 0.f, ci = 0.f;
            for (int w2 = 0; w2 < w; ++w2) {
                float2 e = Es[w2][n];
                float nr = fmaf(Q16.x, cr, fmaf(-Q16.y, ci, e.x));
                float ni = fmaf(Q16.x, ci, fmaf(Q16.y, cr, e.y));
                cr = nr; ci = ni;
            }
            float sr = cr, si = ci;
            #pragma unroll
            for (int jc = 0; jc < 16; ++jc) {
                unsigned int* p = (unsigned int*)&Ss[(16 * w + jc) * 136 + 2 * n];
                unsigned int d = *p;
                *p = pack2(sr, si);
                float dr = bf2f((unsigned short)(d & 0xffff));
                float di = bf2f((unsigned short)(d >> 16));
                float nr = fmaf(lamQ.x, sr, fmaf(-lamQ.y, si, dr));
                float ni = fmaf(lamQ.x, si, fmaf(lamQ.y, sr, di));
                sr = nr; si = ni;
            }
        }
        __syncthreads();
    };

    // --- per-batch: Y = T@V + E@Shat ; gelu ; store g' (blocked layout) ---
    auto gemm2_epi = [&](int bb) {
        floatx4 a2[4];
        #pragma unroll
        for (int nt = 0; nt < 4; ++nt) a2[nt] = (floatx4){0.f, 0.f, 0.f, 0.f};
        #pragma unroll
        for (int kt = 0; kt < 2; ++kt) {
            bf16x8 a = *(const bf16x8*)&Ts[(16 * w + lm) * 72 + kt * 32 + lq * 8];
            #pragma unroll
            for (int nt = 0; nt < 4; ++nt) {
                bf16x8 b = *(const bf16x8*)&Vs[(nt * 16 + lm) * 72 + kt * 32 + lq * 8];
                a2[nt] = __builtin_amdgcn_mfma_f32_16x16x32_bf16(a, b, a2[nt], 0, 0, 0);
            }
        }
        #pragma unroll
        for (int kt = 0; kt < 4; ++kt) {
            bf16x8 a = *(const bf16x8*)&Ps[(16 * w + lm + 1) * 136 + kt * 32 + lq * 8];
            #pragma unroll
            for (int nt = 0; nt < 4; ++nt) {
                bf16x8 b = *(const bf16x8*)&Ss[(nt * 16 + lm) * 136 + kt * 32 + lq * 8];
                a2[nt] = __builtin_amdgcn_mfma_f32_16x16x32_bf16(a, b, a2[nt], 0, 0, 0);
            }
        }
        __syncthreads();   // RY readers done; safe to write ybuf
        #pragma unroll
        for (int nt = 0; nt < 4; ++nt) {
            const int chunk = nt * 16 + lm;
            float gg[4];
            #pragma unroll
            for (int r = 0; r < 4; ++r) {
                const int tt = 16 * w + lq * 4 + r;
                const float vv = bf2f(Vs[chunk * 72 + tt]);
                gg[r] = gelu_fast(fmaf(Dc, vv, a2[nt][r]));
            }
            const int p0 = 8 * w + 2 * lq;
            ybuf[chunk * 34 + p0]     = pack2(gg[0], gg[1]);
            ybuf[chunk * 34 + p0 + 1] = pack2(gg[2], gg[3]);
        }
        __syncthreads();
        unsigned int* gp = (unsigned int*)gprime
                         + (size_t)bb * 32 * 1024 * 64 + (size_t)c * 64;
        #pragma unroll
        for (int q = 0; q < 8; ++q) {
            const int idx = q * 256 + t;               // 0..2047, l = 2*idx
            const int lt = idx >> 6, w32 = idx & 63;
            gp[(size_t)lt * (1024 * 64) + w32] = ybuf[(idx >> 5) * 34 + (idx & 31)];
        }
        __syncthreads();
    };

    // ---- pipeline ----
    deltascan(0);

    {   // P rows tt: (Re,-Im) of 2*Ct*lam^tt ; wave w covers [16w,16w+16) (+row 64 on w=3)
        c32 z = cmul((c32){c2r, -c2mi}, cpow16(lam, w));
        const int steps = (w == 3) ? 17 : 16;
        for (int s = 0; s < steps; ++s) {
            const int tt = 16 * w + s;
            *(unsigned int*)&Ps[tt * 136 + 2 * n] = pack2(z.x, -z.y);
            z = cmul(z, lam);
        }
    }
    {   // R rows u: (Re,Im) lam^-u  (overwrites F, dead post-Delta0)
        c32 z = cpow16(inv, w);
        #pragma unroll
        for (int s = 0; s < 16; ++s) {
            const int u = 16 * w + s;
            *(unsigned int*)&Rs[u * 136 + 2 * n] = pack2(z.x, z.y);
            z = cmul(z, inv);
        }
    }
    __syncthreads();
    {   // GEMM1: T = tril(P@R), M=N=64, K=128  (once per channel)
        floatx4 a1[4];
        #pragma unroll
        for (int nt = 0; nt < 4; ++nt) a1[nt] = (floatx4){0.f, 0.f, 0.f, 0.f};
        #pragma unroll
        for (int kt = 0; kt < 4; ++kt) {
            bf16x8 a = *(const bf16x8*)&Ps[(16 * w + lm) * 136 + kt * 32 + lq * 8];
            #pragma unroll
            for (int nt = 0; nt < 4; ++nt) {
                bf16x8 b = *(const bf16x8*)&Rs[(nt * 16 + lm) * 136 + kt * 32 + lq * 8];
                a1[nt] = __builtin_amdgcn_mfma_f32_16x16x32_bf16(a, b, a1[nt], 0, 0, 0);
            }
        }
        #pragma unroll
        for (int nt = 0; nt < 4; ++nt)
            #pragma unroll
            for (int r = 0; r < 4; ++r) {
                const int row = 16 * w + lq * 4 + r, col = nt * 16 + lm;
                Ts[row * 72 + col] = f2bf(row >= col ? a1[nt][r] : 0.f);
            }
    }
    __syncthreads();

    gemm2_epi(0);
    deltascan(1);
    gemm2_epi(1);
}

// ---------------------------------------------------------------------------
// GEMM: out[b,o,l] = sum_k Wt[o,k]*g'[b,lt,k,l'] + b_out[o].
// 64(o) x 128(l) tiles, BK=64, register prefetch.
// Grid (l-tile=32 fastest, o-tile=8, b): the 8 blocks sharing a B-panel are
// spaced 32 apart in linear ID -> same XCD residue -> panel cached once/XCD.
// ---------------------------------------------------------------------------
__global__ __launch_bounds__(256) void gemm_kernel(
    const unsigned short* __restrict__ gp, const unsigned short* __restrict__ Wt,
    const float* __restrict__ b_out, float* __restrict__ out)
{
    __shared__ unsigned short As[64 * 72];      // [o][k] rows, stride 144 B
    __shared__ unsigned short Bs[128 * 72];     // [l][k]
    const int t = threadIdx.x, lane = t & 63, w = t >> 6;
    const int lm = lane & 15, lq = lane >> 4;
    const int by = blockIdx.x;                  // l-tile 0..31 (fastest)
    const int o0 = blockIdx.y * 64;
    const int bb = blockIdx.z;
    const int l0 = by * 128;
    const unsigned short* bsrc = gp + (size_t)(bb * 32 + by) * (1024 * 128);

    const int kp = t & 31, bg = t >> 5;         // B: k-pair 0..31, l-octet 0..7

    uint4 aR[2], bR[4];
    auto loadA = [&](int k0) {
        #pragma unroll
        for (int h = 0; h < 2; ++h) {
            const int idx = t + h * 256, row = idx >> 3, q = idx & 7;
            aR[h] = *(const uint4*)(Wt + (size_t)(o0 + row) * H_CH + k0 + q * 8);
        }
    };
    auto loadB = [&](int k0) {
        const unsigned short* s0 = bsrc + (size_t)(k0 + 2 * kp) * 128 + bg * 16;
        bR[0] = *(const uint4*)(s0);
        bR[1] = *(const uint4*)(s0 + 8);
        bR[2] = *(const uint4*)(s0 + 128);
        bR[3] = *(const uint4*)(s0 + 136);
    };

    floatx4 acc[4][2];
    #pragma unroll
    for (int i = 0; i < 4; ++i)
        #pragma unroll
        for (int jj = 0; jj < 2; ++jj) acc[i][jj] = (floatx4){0.f, 0.f, 0.f, 0.f};

    loadA(0); loadB(0);
    for (int kt = 0; kt < 16; ++kt) {
        if (kt) __syncthreads();
        {   // store A
            #pragma unroll
            for (int h = 0; h < 2; ++h) {
                const int idx = t + h * 256, row = idx >> 3, q = idx & 7;
                *(uint4*)&As[row * 72 + q * 8] = aR[h];
            }
        }
        {   // transpose-scatter B: Bs[l][k] u32 (k-pair kp)
            unsigned int* bu = (unsigned int*)Bs;
            const unsigned int* a0 = (const unsigned int*)&bR[0];
            const unsigned int* a1 = (const unsigned int*)&bR[1];
            const unsigned int* b0 = (const unsigned int*)&bR[2];
            const unsigned int* b1 = (const unsigned int*)&bR[3];
            #pragma unroll
            for (int i = 0; i < 4; ++i) {
                unsigned int lo0 = (a0[i] & 0xffffu) | (b0[i] << 16);
                unsigned int hi0 = (a0[i] >> 16) | (b0[i] & 0xffff0000u);
                unsigned int lo1 = (a1[i] & 0xffffu) | (b1[i] << 16);
                unsigned int hi1 = (a1[i] >> 16) | (b1[i] & 0xffff0000u);
                bu[(bg * 16 + 2 * i) * 36 + kp]     = lo0;
                bu[(bg * 16 + 2 * i + 1) * 36 + kp] = hi0;
                bu[(bg * 16 + 8 + 2 * i) * 36 + kp]     = lo1;
                bu[(bg * 16 + 8 + 2 * i + 1) * 36 + kp] = hi1;
            }
        }
        __syncthreads();
        if (kt < 15) { loadA((kt + 1) * 64); loadB((kt + 1) * 64); }

        #pragma unroll
        for (int q2 = 0; q2 < 2; ++q2) {
            bf16x8 af[4], bfr[2];
            #pragma unroll
            for (int sm = 0; sm < 4; ++sm)
                af[sm] = *(const bf16x8*)&As[(sm * 16 + lm) * 72 + q2 * 32 + lq * 8];
            #pragma unroll
            for (int sn = 0; sn < 2; ++sn)
                bfr[sn] = *(const bf16x8*)&Bs[(w * 32 + sn * 16 + lm) * 72 + q2 * 32 + lq * 8];
            #pragma unroll
            for (int sm = 0; sm < 4; ++sm)
                #pragma unroll
                for (int sn = 0; sn < 2; ++sn)
                    acc[sm][sn] = __builtin_amdgcn_mfma_f32_16x16x32_bf16(
                        af[sm], bfr[sn], acc[sm][sn], 0, 0, 0);
        }
    }

    #pragma unroll
    for (int sm = 0; sm < 4; ++sm)
        #pragma unroll
        for (int sn = 0; sn < 2; ++sn)
            #pragma unroll
            for (int r = 0; r < 4; ++r) {
                const int o = o0 + sm * 16 + lq * 4 + r;
                const int l = l0 + w * 32 + sn * 16 + lm;
                out[((size_t)bb * OUTF + o) * LSEQ + l] = acc[sm][sn][r] + b_out[o];
            }
}

// ---------------------------------------------------------------------------
extern "C" void kernel_launch(void* const* d_in, const int* in_sizes, int n_in,
                              void* d_out, int out_size, void* d_ws, size_t ws_size,
                              hipStream_t stream) {
    const float* x      = (const float*)d_in[0];
    const float* log_dt = (const float*)d_in[1];
    const float* A_re   = (const float*)d_in[2];
    const float* A_im   = (const float*)d_in[3];
    const float* C_re   = (const float*)d_in[4];
    const float* C_im   = (const float*)d_in[5];
    const float* Dp     = (const float*)d_in[6];
    const float* W_out  = (const float*)d_in[7];
    const float* b_out  = (const float*)d_in[8];
    float* out = (float*)d_out;

    // Workspace: g' [0,16M), Wt [17M,18M), coef [19M,21M)
    char* ws = (char*)d_ws;
    unsigned short* gprime = (unsigned short*)ws;
    unsigned short* Wt     = (unsigned short*)(ws + (size_t)17 * 1024 * 1024);
    float*          coef   = (float*)(ws + (size_t)19 * 1024 * 1024);

    prep_kernel<<<384, 256, 0, stream>>>(log_dt, A_re, A_im, C_re, C_im, W_out,
                                         coef, Wt);
    s4_fused_kernel<<<1024, 256, 0, stream>>>(x, coef, Dp, gprime);
    gemm_kernel<<<dim3(32, 8, 2), 256, 0, stream>>>(gprime, Wt, b_out, out);
}

// Round 10
// 144.053 us; speedup vs baseline: 1.0561x; 1.0503x over previous
//
#include <hip/hip_runtime.h>
#include <cstdint>
#include <cstddef>

#define H_CH 1024
#define OUTF 512
#define LSEQ 4096

typedef __bf16 bf16x8 __attribute__((ext_vector_type(8)));
typedef float floatx4 __attribute__((ext_vector_type(4)));

__device__ __forceinline__ unsigned short f2bf(float f) {
    __bf16 b = (__bf16)f;
    return __builtin_bit_cast(unsigned short, b);
}
__device__ __forceinline__ unsigned int pack2(float a, float b) {
    return (unsigned int)f2bf(a) | ((unsigned int)f2bf(b) << 16);
}
__device__ __forceinline__ float bf2f(unsigned short u) {
    unsigned int x = ((unsigned int)u) << 16;
    return __builtin_bit_cast(float, x);
}
struct c32 { float x, y; };
__device__ __forceinline__ c32 cmul(c32 a, c32 b) {
    return { fmaf(a.x, b.x, -a.y * b.y), fmaf(a.x, b.y, a.y * b.x) };
}
__device__ __forceinline__ c32 cpow16(c32 a, int w) {   // a^(16*w), w in 0..3
    c32 p = {1.f, 0.f};
    if (w) {
        c32 a2 = cmul(a, a), a4 = cmul(a2, a2), a8 = cmul(a4, a4), a16 = cmul(a8, a8);
        p = a16;
        for (int k = 1; k < w; ++k) p = cmul(p, a16);
    }
    return p;
}
// gelu(y) = y * sigmoid(1.59576912*(y + 0.044715 y^3))  (== tanh-GELU exactly)
__device__ __forceinline__ float gelu_fast(float y) {
    float u = y + 0.044715f * y * y * y;
    float e = __expf(-1.5957691216057308f * u);
    return y * __builtin_amdgcn_rcpf(1.f + e);
}

// ---------------------------------------------------------------------------
// prep: blocks 0..255 -> coef per (c,n); blocks 256..383 -> W transpose.
// coef = fp64-exact {lam, inv=lam^-1, lamQ=lam^64, 2*conj-folded Ct}.
// ---------------------------------------------------------------------------
__global__ __launch_bounds__(256) void prep_kernel(
    const float* __restrict__ log_dt, const float* __restrict__ A_re,
    const float* __restrict__ A_im, const float* __restrict__ C_re,
    const float* __restrict__ C_im, const float* __restrict__ W,
    float* __restrict__ coef, unsigned short* __restrict__ Wt)
{
    __shared__ float tileF[64 * 65];
    const int t = threadIdx.x;
    if (blockIdx.x < 256) {
        const int i = blockIdx.x * 256 + t;             // c*64+n
        const int c = i >> 6;
        double are = A_re[i], aim = A_im[i], cre = C_re[i], cim = C_im[i];
        double dt  = exp((double)log_dt[c]);
        double dar = dt * are, dai = dt * aim;
        double er = exp(dar), cd = cos(dai), sd = sin(dai);
        double lre = er * cd, limm = er * sd;
        double ei = exp(-dar);
        double eQ = exp(64.0 * dar), cQ = cos(64.0 * dai), sQ = sin(64.0 * dai);
        double nre = lre - 1.0, nim = limm;
        double d2  = are * are + aim * aim;
        double qre = (nre * are + nim * aim) / d2;
        double qim = (nim * are - nre * aim) / d2;
        double ctre = cre * qre - cim * qim, ctim = cre * qim + cim * qre;
        float4 w0 = make_float4((float)lre, (float)limm, (float)(ei * cd), (float)(-ei * sd));
        float4 w1 = make_float4((float)(eQ * cQ), (float)(eQ * sQ),
                                (float)(2.0 * ctre), (float)(-2.0 * ctim));
        *(float4*)&coef[(size_t)i * 8]     = w0;
        *(float4*)&coef[(size_t)i * 8 + 4] = w1;
    } else {
        const int bid = blockIdx.x - 256;               // 0..127
        const int o0 = (bid & 7) * 64, k0 = (bid >> 3) * 64;
        {
            const int ty = t >> 6, tx = t & 63;
            #pragma unroll
            for (int r = 0; r < 16; ++r) {
                const int ki = r * 4 + ty;
                tileF[ki * 65 + tx] = W[(size_t)(k0 + ki) * OUTF + o0 + tx];
            }
        }
        __syncthreads();
        {
            const int ty = t >> 5, tx = t & 31;
            #pragma unroll
            for (int r = 0; r < 8; ++r) {
                const int oi = r * 8 + ty;
                unsigned int u0 = f2bf(tileF[(2 * tx) * 65 + oi]);
                unsigned int u1 = f2bf(tileF[(2 * tx + 1) * 65 + oi]);
                *(unsigned int*)&Wt[(size_t)(o0 + oi) * H_CH + k0 + 2 * tx] = u0 | (u1 << 16);
            }
        }
    }
}

// ---------------------------------------------------------------------------
// s4_fused: one block per channel c, loops over both batches.  (R6-exact)
// Output g' in l-tile-blocked layout: g'[b][l>>7][c][l&127] (bf16).
// ---------------------------------------------------------------------------
__global__ __launch_bounds__(256) void s4_fused_kernel(
    const float* __restrict__ x, const float* __restrict__ coef,
    const float* __restrict__ Dp, unsigned short* __restrict__ gprime)
{
    __shared__ __align__(16) unsigned short Vs[64 * 72];      // [chunk][t]
    __shared__ __align__(16) unsigned short Ps[65 * 136];     // P rows (bf16 pairs)
    __shared__ __align__(16) unsigned char  RY[128 * 72 * 2]; // F / R / ybuf overlay
    __shared__ __align__(16) unsigned short Ss[64 * 136];     // Delta -> Shat
    __shared__ __align__(16) unsigned short Ts[64 * 72];      // T = tril(P@R) bf16
    __shared__ float2 Es[4][64];
    __shared__ float  pe16[16];
    unsigned short* Fs   = (unsigned short*)RY;               // 128*72
    unsigned short* Rs   = (unsigned short*)RY;               // 64*136
    unsigned int*   ybuf = (unsigned int*)RY;                 // 64*34 u32

    const int c = blockIdx.x;                                 // 0..1023
    const int t = threadIdx.x, lane = t & 63, w = t >> 6, n = lane;
    const int lm = lane & 15, lq = lane >> 4;

    const int axis = (c >= 684) ? 2 : ((c >= 342) ? 1 : 0);
    const int j = c - 342 * axis;
    const int is_cos = j & 1;
    if (t < 16) {
        const float freq = (float)exp(-log(10000.0) * (double)(2 * (j >> 1)) / 342.0);
        float a = (float)t * freq;
        pe16[t] = is_cos ? cosf(a) : sinf(a);
    }
    const float* cf = coef + ((size_t)c * 64 + n) * 8;
    c32 lam = {cf[0], cf[1]}, inv = {cf[2], cf[3]}, lamQ = {cf[4], cf[5]};
    const float c2r = cf[6], c2mi = cf[7];
    const float Dc = Dp[c];
    __syncthreads();                                          // pe16 visible

    // --- per-batch: stage V, gen F, Delta, segmented scan -> Shat in Ss ---
    auto deltascan = [&](int bb) {
        const float* xp = x + ((size_t)bb * H_CH + c) * (size_t)LSEQ;
        #pragma unroll
        for (int r = 0; r < 2; ++r) {
            const int i = r * 256 + t, l0 = i * 8;
            float4 f0 = *(const float4*)(xp + l0);
            float4 f1 = *(const float4*)(xp + l0 + 4);
            float e[8] = {f0.x, f0.y, f0.z, f0.w, f1.x, f1.y, f1.z, f1.w};
            unsigned int o[4];
            #pragma unroll
            for (int k = 0; k < 4; ++k) {
                const int la = l0 + 2 * k, lb = la + 1;
                const int pa = axis == 0 ? (la >> 8) : axis == 1 ? ((la >> 4) & 15) : (la & 15);
                const int pb = axis == 0 ? (lb >> 8) : axis == 1 ? ((lb >> 4) & 15) : (lb & 15);
                o[k] = pack2(e[2 * k] + pe16[pa], e[2 * k + 1] + pe16[pb]);
            }
            *(uint4*)&Vs[(i >> 3) * 72 + (i & 7) * 8] = make_uint4(o[0], o[1], o[2], o[3]);
        }
        {   // F rows 2n,2n+1: (Re,Im) lam^(63-u), u in [16w,16w+16)
            c32 l2 = cmul(lam, lam), l4 = cmul(l2, l2), l8 = cmul(l4, l4);
            c32 l16 = cmul(l8, l8), l32 = cmul(l16, l16);
            c32 z = cmul(cmul(cmul(cmul(cmul(l32, l16), l8), l4), l2), lam); // lam^63
            z = cmul(z, cpow16(inv, w));
            #pragma unroll
            for (int s = 0; s < 16; ++s) {
                const int u = 16 * w + s;
                Fs[(2 * n) * 72 + u]     = f2bf(z.x);
                Fs[(2 * n + 1) * 72 + u] = f2bf(z.y);
                z = cmul(z, inv);
            }
        }
        __syncthreads();
        {   // Delta = F(128x64) @ V(64x64) -> scatter into Ss [chunk][comp]
            floatx4 acc[2][4];
            #pragma unroll
            for (int a = 0; a < 2; ++a)
                #pragma unroll
                for (int b = 0; b < 4; ++b) acc[a][b] = (floatx4){0.f, 0.f, 0.f, 0.f};
            #pragma unroll
            for (int kt = 0; kt < 2; ++kt) {
                bf16x8 a0 = *(const bf16x8*)&Fs[(32 * w + lm) * 72 + kt * 32 + lq * 8];
                bf16x8 a1 = *(const bf16x8*)&Fs[(32 * w + 16 + lm) * 72 + kt * 32 + lq * 8];
                #pragma unroll
                for (int nt = 0; nt < 4; ++nt) {
                    bf16x8 b = *(const bf16x8*)&Vs[(nt * 16 + lm) * 72 + kt * 32 + lq * 8];
                    acc[0][nt] = __builtin_amdgcn_mfma_f32_16x16x32_bf16(a0, b, acc[0][nt], 0, 0, 0);
                    acc[1][nt] = __builtin_amdgcn_mfma_f32_16x16x32_bf16(a1, b, acc[1][nt], 0, 0, 0);
                }
            }
            #pragma unroll
            for (int sm = 0; sm < 2; ++sm)
                #pragma unroll
                for (int nt = 0; nt < 4; ++nt) {
                    const int row = 32 * w + sm * 16 + lq * 4, col = nt * 16 + lm;
                    *(uint2*)&Ss[col * 136 + row] =
                        make_uint2(pack2(acc[sm][nt][0], acc[sm][nt][1]),
                                   pack2(acc[sm][nt][2], acc[sm][nt][3]));
                }
        }
        __syncthreads();
        {   // scan A: local (zero-init) scan of 16-chunk segment
            float sr = 0.f, si = 0.f;
            #pragma unroll
            for (int jc = 0; jc < 16; ++jc) {
                unsigned int d = *(unsigned int*)&Ss[(16 * w + jc) * 136 + 2 * n];
                float dr = bf2f((unsigned short)(d & 0xffff));
                float di = bf2f((unsigned short)(d >> 16));
                float nr = fmaf(lamQ.x, sr, fmaf(-lamQ.y, si, dr));
                float ni = fmaf(lamQ.x, si, fmaf(lamQ.y, sr, di));
                sr = nr; si = ni;
            }
            Es[w][n] = make_float2(sr, si);
        }
        __syncthreads();
        {   // carry + scan B -> exclusive Shat written back to Ss
            c32 Q2 = cmul(lamQ, lamQ), Q4 = cmul(Q2, Q2), Q8 = cmul(Q4, Q4);
            c32 Q16 = cmul(Q8, Q8);                       // lam^1024
            float cr = 0.f, ci = 0.f;
            for (int w2 = 0; w2 < w; ++w2) {
                float2 e = Es[w2][n];
                float nr = fmaf(Q16.x, cr, fmaf(-Q16.y, ci, e.x));
                float ni = fmaf(Q16.x, ci, fmaf(Q16.y, cr, e.y));
                cr = nr; ci = ni;
            }
            float sr = cr, si = ci;
            #pragma unroll
            for (int jc = 0; jc < 16; ++jc) {
                unsigned int* p = (unsigned int*)&Ss[(16 * w + jc) * 136 + 2 * n];
                unsigned int d = *p;
                *p = pack2(sr, si);
                float dr = bf2f((unsigned short)(d & 0xffff));
                float di = bf2f((unsigned short)(d >> 16));
                float nr = fmaf(lamQ.x, sr, fmaf(-lamQ.y, si, dr));
                float ni = fmaf(lamQ.x, si, fmaf(lamQ.y, sr, di));
                sr = nr; si = ni;
            }
        }
        __syncthreads();
    };

    // --- per-batch: Y = T@V + E@Shat ; gelu ; store g' (blocked layout) ---
    auto gemm2_epi = [&](int bb) {
        floatx4 a2[4];
        #pragma unroll
        for (int nt = 0; nt < 4; ++nt) a2[nt] = (floatx4){0.f, 0.f, 0.f, 0.f};
        #pragma unroll
        for (int kt = 0; kt < 2; ++kt) {
            bf16x8 a = *(const bf16x8*)&Ts[(16 * w + lm) * 72 + kt * 32 + lq * 8];
            #pragma unroll
            for (int nt = 0; nt < 4; ++nt) {
                bf16x8 b = *(const bf16x8*)&Vs[(nt * 16 + lm) * 72 + kt * 32 + lq * 8];
                a2[nt] = __builtin_amdgcn_mfma_f32_16x16x32_bf16(a, b, a2[nt], 0, 0, 0);
            }
        }
        #pragma unroll
        for (int kt = 0; kt < 4; ++kt) {
            bf16x8 a = *(const bf16x8*)&Ps[(16 * w + lm + 1) * 136 + kt * 32 + lq * 8];
            #pragma unroll
            for (int nt = 0; nt < 4; ++nt) {
                bf16x8 b = *(const bf16x8*)&Ss[(nt * 16 + lm) * 136 + kt * 32 + lq * 8];
                a2[nt] = __builtin_amdgcn_mfma_f32_16x16x32_bf16(a, b, a2[nt], 0, 0, 0);
            }
        }
        __syncthreads();   // RY readers done; safe to write ybuf
        #pragma unroll
        for (int nt = 0; nt < 4; ++nt) {
            const int chunk = nt * 16 + lm;
            float gg[4];
            #pragma unroll
            for (int r = 0; r < 4; ++r) {
                const int tt = 16 * w + lq * 4 + r;
                const float vv = bf2f(Vs[chunk * 72 + tt]);
                gg[r] = gelu_fast(fmaf(Dc, vv, a2[nt][r]));
            }
            const int p0 = 8 * w + 2 * lq;
            ybuf[chunk * 34 + p0]     = pack2(gg[0], gg[1]);
            ybuf[chunk * 34 + p0 + 1] = pack2(gg[2], gg[3]);
        }
        __syncthreads();
        unsigned int* gp = (unsigned int*)gprime
                         + (size_t)bb * 32 * 1024 * 64 + (size_t)c * 64;
        #pragma unroll
        for (int q = 0; q < 8; ++q) {
            const int idx = q * 256 + t;               // 0..2047, l = 2*idx
            const int lt = idx >> 6, w32 = idx & 63;
            gp[(size_t)lt * (1024 * 64) + w32] = ybuf[(idx >> 5) * 34 + (idx & 31)];
        }
        __syncthreads();
    };

    // ---- pipeline ----
    deltascan(0);

    {   // P rows tt: (Re,-Im) of 2*Ct*lam^tt ; wave w covers [16w,16w+16) (+row 64 on w=3)
        c32 z = cmul((c32){c2r, -c2mi}, cpow16(lam, w));
        const int steps = (w == 3) ? 17 : 16;
        for (int s = 0; s < steps; ++s) {
            const int tt = 16 * w + s;
            *(unsigned int*)&Ps[tt * 136 + 2 * n] = pack2(z.x, -z.y);
            z = cmul(z, lam);
        }
    }
    {   // R rows u: (Re,Im) lam^-u  (overwrites F, dead post-Delta0)
        c32 z = cpow16(inv, w);
        #pragma unroll
        for (int s = 0; s < 16; ++s) {
            const int u = 16 * w + s;
            *(unsigned int*)&Rs[u * 136 + 2 * n] = pack2(z.x, z.y);
            z = cmul(z, inv);
        }
    }
    __syncthreads();
    {   // GEMM1: T = tril(P@R), M=N=64, K=128  (once per channel)
        floatx4 a1[4];
        #pragma unroll
        for (int nt = 0; nt < 4; ++nt) a1[nt] = (floatx4){0.f, 0.f, 0.f, 0.f};
        #pragma unroll
        for (int kt = 0; kt < 4; ++kt) {
            bf16x8 a = *(const bf16x8*)&Ps[(16 * w + lm) * 136 + kt * 32 + lq * 8];
            #pragma unroll
            for (int nt = 0; nt < 4; ++nt) {
                bf16x8 b = *(const bf16x8*)&Rs[(nt * 16 + lm) * 136 + kt * 32 + lq * 8];
                a1[nt] = __builtin_amdgcn_mfma_f32_16x16x32_bf16(a, b, a1[nt], 0, 0, 0);
            }
        }
        #pragma unroll
        for (int nt = 0; nt < 4; ++nt)
            #pragma unroll
            for (int r = 0; r < 4; ++r) {
                const int row = 16 * w + lq * 4 + r, col = nt * 16 + lm;
                Ts[row * 72 + col] = f2bf(row >= col ? a1[nt][r] : 0.f);
            }
    }
    __syncthreads();

    gemm2_epi(0);
    deltascan(1);
    gemm2_epi(1);
}

// ---------------------------------------------------------------------------
// GEMM (R6-exact, measured best): out[b,o,l] = sum_k Wt[o,k]*g'[..] + b_out[o].
// 64(o) x 128(l) tiles, BK=32, register prefetch, in-LDS B transpose.
// ---------------------------------------------------------------------------
__global__ __launch_bounds__(256) void gemm_kernel(
    const unsigned short* __restrict__ gp, const unsigned short* __restrict__ Wt,
    const float* __restrict__ b_out, float* __restrict__ out)
{
    __shared__ unsigned short As[64 * 40];      // [o][k] rows padded to 80B
    __shared__ unsigned short Bs[128 * 40];     // [l][k]
    const int t = threadIdx.x, lane = t & 63, w = t >> 6;
    const int lm = lane & 15, lq = lane >> 4;
    const int bx = blockIdx.x;                  // l-tile 0..31
    const int o0 = blockIdx.y * 64;
    const int bb = blockIdx.z;
    const int l0 = bx * 128;
    const unsigned short* bsrc = gp + (size_t)(bb * 32 + bx) * (1024 * 128);

    const int arow = t >> 2, aq = t & 3;        // A staging role
    const int bp = t & 15, bgq = t >> 4;        // B staging: k-pair, l-octet

    uint4 areg, breg0, breg1;
    {
        areg  = *(const uint4*)(Wt + (size_t)(o0 + arow) * H_CH + aq * 8);
        const unsigned short* b0 = bsrc + (size_t)(2 * bp) * 128 + bgq * 8;
        breg0 = *(const uint4*)(b0);
        breg1 = *(const uint4*)(b0 + 128);
    }

    floatx4 acc[4][2];
    #pragma unroll
    for (int i = 0; i < 4; ++i)
        #pragma unroll
        for (int jj = 0; jj < 2; ++jj) acc[i][jj] = (floatx4){0.f, 0.f, 0.f, 0.f};

    for (int kt = 0; kt < 32; ++kt) {
        if (kt) __syncthreads();                // prev iter's LDS reads done
        *(uint4*)&As[arow * 40 + aq * 8] = areg;
        {   // transpose-scatter: Bs[l][k] u32 pairs (k=2bp, 2bp+1)
            unsigned int* bu = (unsigned int*)Bs;
            const unsigned int* a = (const unsigned int*)&breg0;
            const unsigned int* b = (const unsigned int*)&breg1;
            #pragma unroll
            for (int i = 0; i < 4; ++i) {
                unsigned int lo = (a[i] & 0xffffu) | (b[i] << 16);
                unsigned int hi = (a[i] >> 16) | (b[i] & 0xffff0000u);
                bu[(bgq * 8 + 2 * i) * 20 + bp]     = lo;
                bu[(bgq * 8 + 2 * i + 1) * 20 + bp] = hi;
            }
        }
        __syncthreads();
        if (kt < 31) {                          // prefetch next k-tile
            const int k0 = (kt + 1) * 32;
            areg  = *(const uint4*)(Wt + (size_t)(o0 + arow) * H_CH + k0 + aq * 8);
            const unsigned short* b0 = bsrc + (size_t)(k0 + 2 * bp) * 128 + bgq * 8;
            breg0 = *(const uint4*)(b0);
            breg1 = *(const uint4*)(b0 + 128);
        }

        bf16x8 af[4], bfr[2];
        #pragma unroll
        for (int sm = 0; sm < 4; ++sm)
            af[sm] = *(const bf16x8*)&As[(sm * 16 + lm) * 40 + lq * 8];
        #pragma unroll
        for (int sn = 0; sn < 2; ++sn)
            bfr[sn] = *(const bf16x8*)&Bs[(w * 32 + sn * 16 + lm) * 40 + lq * 8];
        #pragma unroll
        for (int sm = 0; sm < 4; ++sm)
            #pragma unroll
            for (int sn = 0; sn < 2; ++sn)
                acc[sm][sn] = __builtin_amdgcn_mfma_f32_16x16x32_bf16(
                    af[sm], bfr[sn], acc[sm][sn], 0, 0, 0);
    }

    #pragma unroll
    for (int sm = 0; sm < 4; ++sm)
        #pragma unroll
        for (int sn = 0; sn < 2; ++sn)
            #pragma unroll
            for (int r = 0; r < 4; ++r) {
                const int o = o0 + sm * 16 + lq * 4 + r;
                const int l = l0 + w * 32 + sn * 16 + lm;
                out[((size_t)bb * OUTF + o) * LSEQ + l] = acc[sm][sn][r] + b_out[o];
            }
}

// ---------------------------------------------------------------------------
extern "C" void kernel_launch(void* const* d_in, const int* in_sizes, int n_in,
                              void* d_out, int out_size, void* d_ws, size_t ws_size,
                              hipStream_t stream) {
    const float* x      = (const float*)d_in[0];
    const float* log_dt = (const float*)d_in[1];
    const float* A_re   = (const float*)d_in[2];
    const float* A_im   = (const float*)d_in[3];
    const float* C_re   = (const float*)d_in[4];
    const float* C_im   = (const float*)d_in[5];
    const float* Dp     = (const float*)d_in[6];
    const float* W_out  = (const float*)d_in[7];
    const float* b_out  = (const float*)d_in[8];
    float* out = (float*)d_out;

    // Workspace: g' [0,16M), Wt [17M,18M), coef [19M,21M)
    char* ws = (char*)d_ws;
    unsigned short* gprime = (unsigned short*)ws;
    unsigned short* Wt     = (unsigned short*)(ws + (size_t)17 * 1024 * 1024);
    float*          coef   = (float*)(ws + (size_t)19 * 1024 * 1024);

    prep_kernel<<<384, 256, 0, stream>>>(log_dt, A_re, A_im, C_re, C_im, W_out,
                                         coef, Wt);
    s4_fused_kernel<<<1024, 256, 0, stream>>>(x, coef, Dp, gprime);
    gemm_kernel<<<dim3(32, 8, 2), 256, 0, stream>>>(gprime, Wt, b_out, out);
}